// Round 12
// baseline (440.417 us; speedup 1.0000x reference)
//
#include <hip/hip_runtime.h>
#include <stdint.h>

// PROBE ROUND (NREP=3, idempotent recompute): exact R11 structure (157us,
// raw v_exp_f32 activations, 2-chain FC-merged, 2 barriers/step) repeated
// 3x inside the kernel so the dispatch clears the ~320us fill band and
// returns counters for the POST-exp2fix kernel. One variable vs R11.
//
// Chain A = p 0..31 (n-tiles 0,1), chain B = p 32..63 (n-tiles 2,3).
//   P1: gather-issue(t+1), GEMM_A(t)+FC_A(t-1) merged, cell_B(t-1)
//   P2: GEMM_B(t)+FC_B(t-1) merged, cell_A(t), x-pack(t+1)
// Weights + bias persistent in VGPRs; x/h LDS pre-packed as MFMA B-frags
// (conflict-free ds_read_b128), double-buffered. exp2-folded activations.

#define T_STEPS 32
#define C_IN    64
#define HID     128
#define OUT_F   64
#define BP      64
#define NBLK    256            // 16384 / BP
#define NTHR    512            // 8 waves
#define NREP    3              // profiling repeat

typedef __attribute__((ext_vector_type(8))) short short8_t;
typedef __attribute__((ext_vector_type(4))) short short4_t;
typedef __attribute__((ext_vector_type(4))) float float4_t;
typedef __attribute__((ext_vector_type(4))) unsigned int uint4_t;

#define L2E 1.44269504088896340736f

__device__ __forceinline__ short f2bf(float f) {
    uint32_t u = __builtin_bit_cast(uint32_t, f);
    u += 0x7fff + ((u >> 16) & 1);   // RNE
    return (short)(u >> 16);
}
__device__ __forceinline__ uint32_t cvt_pk(float lo, float hi) {
    uint32_t r;
    asm("v_cvt_pk_bf16_f32 %0, %1, %2" : "=v"(r) : "v"(lo), "v"(hi));
    return r;
}
// raw-trans activations: one v_exp_f32 + one v_rcp_f32 each
__device__ __forceinline__ float sig2(float a) {   // a pre-scaled by L2E
    return __builtin_amdgcn_rcpf(1.0f + __builtin_amdgcn_exp2f(-a));
}
__device__ __forceinline__ float th2(float a) {    // a pre-scaled by 2*L2E
    return fmaf(-2.0f,
                __builtin_amdgcn_rcpf(1.0f + __builtin_amdgcn_exp2f(a)),
                1.0f);
}

__global__ __launch_bounds__(NTHR, 2) void lstmconv_mfma(
    const float* __restrict__ feats,
    const float* __restrict__ W_ih,
    const float* __restrict__ W_hh,
    const float* __restrict__ b_ih,
    const float* __restrict__ b_hh,
    const float* __restrict__ fc_w,
    const float* __restrict__ fc_b,
    float* __restrict__ out)
{
    __shared__ __align__(16) short xB[2][8][512];    // 16 KB
    __shared__ __align__(16) short hB[2][16][512];   // 32 KB

    const int tid  = threadIdx.x;
    const int lane = tid & 63;
    const int wv   = tid >> 6;       // wave 0..7; owns gate rows 16wv..16wv+16
    const int i16  = lane & 15;
    const int g4   = lane >> 4;
    const int p0   = blockIdx.x * BP;

    // Gate-W A-fragments, persistent, log2e-scaled:
    // row = 128*gi + 16*wv + i16 ; k = 32*kt + 8*g4 + e  (kt<2 -> W_ih)
    short8_t wfrag[4][6];
    float4_t bias_r[4];
    #pragma unroll
    for (int gi = 0; gi < 4; ++gi) {
        int row = 128 * gi + 16 * wv + i16;
        float sc = (gi == 2) ? 2.0f * L2E : L2E;
        #pragma unroll
        for (int kt = 0; kt < 6; ++kt) {
            int kk = 32 * kt + 8 * g4;
            const float* src = (kt < 2) ? &W_ih[row * C_IN + kk]
                                        : &W_hh[row * HID + (kk - 64)];
            short8_t f;
            #pragma unroll
            for (int e = 0; e < 8; ++e) f[e] = f2bf(src[e] * sc);
            wfrag[gi][kt] = f;
        }
        int g0 = 128 * gi + 16 * wv + 4 * g4;
        float4_t bi = *(const float4_t*)&b_ih[g0];
        float4_t bh = *(const float4_t*)&b_hh[g0];
        #pragma unroll
        for (int r = 0; r < 4; ++r) bias_r[gi][r] = (bi[r] + bh[r]) * sc;
    }

    // FC: wave -> m-tile m2=wv&3 (out rows 16m2..+16), local n-tile nl=wv>>2.
    const int m2  = wv & 3;
    const int nl  = wv >> 2;         // 0 or 1 within the chain
    short8_t fcfrag[4];
    #pragma unroll
    for (int kt = 0; kt < 4; ++kt) {
        int kk = 32 * kt + 8 * g4;
        const float* src = &fc_w[(16 * m2 + i16) * HID + kk];
        short8_t f;
        #pragma unroll
        for (int e = 0; e < 8; ++e) f[e] = f2bf(src[e]);
        fcfrag[kt] = f;
    }
    const float4_t fcb = *(const float4_t*)&fc_b[16 * m2 + 4 * g4];

    // gather: thread loads channels c = 8*wv + e, pixel p = lane
    const int prow  = 2 * (p0 >> 7) + 1;
    const int pcol0 = 2 * (p0 & 127) + 1;
    const int gbase = prow * 256 + pcol0 + 2 * lane;
    const int xtile = (wv >> 2) * 4 + (lane >> 4);           // kt*4 + nt
    const int xoff  = ((lane & 15) + 16 * (wv & 3)) * 8;
    const int htile_base = (wv >> 1) * 4;                    // + global nt
    const int hoff  = (i16 + 16 * (2 * (wv & 1) + (g4 >> 1))) * 8 + 4 * (g4 & 1);

    float4_t accA[4][2], accB[4][2], cA[2], cB[2];

    // store FC result for step tf of `chain`
    auto store_fc = [&](int tf, int chain, const float4_t& facc) {
        int ntg = chain * 2 + nl;
        #pragma unroll
        for (int r = 0; r < 4; ++r)
            out[((size_t)(tf * OUT_F + 16 * m2 + 4 * g4 + r) << 14)
                + p0 + 16 * ntg + i16] = facc[r];
    };

    // standalone FC (epilogue): h in hB[hb]
    auto do_fc = [&](int tf, int hb, int chain) {
        int ntg = chain * 2 + nl;
        float4_t facc = fcb;
        #pragma unroll
        for (int kt = 0; kt < 4; ++kt) {
            short8_t b = *(const short8_t*)&hB[hb][kt * 4 + ntg][lane * 8];
            facc = __builtin_amdgcn_mfma_f32_16x16x32_bf16(
                fcfrag[kt], b, facc, 0, 0, 0);
        }
        store_fc(tf, chain, facc);
    };

    // gates = bias + W @ [x(xb); h(hb)] for `chain`; FC(t-1) merged on the
    // shared h fragments (kt 2..5) when nt == nl.
    auto gemm = [&](float4_t (&acc)[4][2], int xb, int hb, int chain,
                    float4_t& facc, bool fc_on) {
        #pragma unroll
        for (int gi = 0; gi < 4; ++gi)
            #pragma unroll
            for (int nt = 0; nt < 2; ++nt) acc[gi][nt] = bias_r[gi];
        #pragma unroll
        for (int nt = 0; nt < 2; ++nt) {
            int ntg = chain * 2 + nt;
            short8_t bf[6];
            #pragma unroll
            for (int kt = 0; kt < 6; ++kt) {
                const short* src = (kt < 2) ? &xB[xb][kt * 4 + ntg][0]
                                            : &hB[hb][(kt - 2) * 4 + ntg][0];
                bf[kt] = *(const short8_t*)&src[lane * 8];
            }
            #pragma unroll
            for (int kt = 0; kt < 6; ++kt)
                #pragma unroll
                for (int gi = 0; gi < 4; ++gi)
                    acc[gi][nt] = __builtin_amdgcn_mfma_f32_16x16x32_bf16(
                        wfrag[gi][kt], bf[kt], acc[gi][nt], 0, 0, 0);
            if (fc_on && nt == nl) {
                #pragma unroll
                for (int kt = 2; kt < 6; ++kt)
                    facc = __builtin_amdgcn_mfma_f32_16x16x32_bf16(
                        fcfrag[kt - 2], bf[kt], facc, 0, 0, 0);
            }
        }
    };

    // cell update (i,f,g,o) for `chain`; writes h into hB[hb]
    auto cell = [&](float4_t (&acc)[4][2], float4_t (&c)[2], int hb, int chain) {
        #pragma unroll
        for (int nt = 0; nt < 2; ++nt) {
            float4_t cv = c[nt];
            float hv[4];
            #pragma unroll
            for (int r = 0; r < 4; ++r) {
                float ig = sig2(acc[0][nt][r]);
                float fg = sig2(acc[1][nt][r]);
                float cand = th2(acc[2][nt][r]);
                float og = sig2(acc[3][nt][r]);
                float cn = fmaf(fg, cv[r], ig * cand);
                cv[r] = cn;
                hv[r] = og * th2(cn * (2.0f * L2E));
            }
            c[nt] = cv;
            uint32_t h0 = cvt_pk(hv[0], hv[1]);
            uint32_t h1 = cvt_pk(hv[2], hv[3]);
            uint32_t* dst = (uint32_t*)&hB[hb][htile_base + chain * 2 + nt][hoff];
            dst[0] = h0; dst[1] = h1;
        }
    };

    #pragma unroll 1
    for (int rep = 0; rep < NREP; ++rep) {
        // zero h_{-1} in BOTH buffers (recurrence restart)
        for (int i = tid; i < 2 * 16 * 512 / 2; i += NTHR)
            ((uint32_t*)hB)[i] = 0u;
        __syncthreads();

        // prologue: gather x_0 -> xB[0]
        {
            float g[8];
            #pragma unroll
            for (int e = 0; e < 8; ++e)
                g[e] = feats[((size_t)(8 * wv + e) << 16) + gbase];
            uint4_t pk = { cvt_pk(g[0], g[1]), cvt_pk(g[2], g[3]),
                           cvt_pk(g[4], g[5]), cvt_pk(g[6], g[7]) };
            *(uint4_t*)&xB[0][xtile][xoff] = pk;
        }
        #pragma unroll
        for (int nt = 0; nt < 2; ++nt) {
            cA[nt] = (float4_t){0.f, 0.f, 0.f, 0.f};
            cB[nt] = (float4_t){0.f, 0.f, 0.f, 0.f};
        }
        __syncthreads();   // xB[0] ready, hB zeroed

        #pragma unroll 1
        for (int t = 0; t < T_STEPS; ++t) {
            const int cur = t & 1;
            const int nxt = cur ^ 1;   // holds h(t-1) of both chains

            // ======== P1: GEMM_A(t)+FC_A(t-1) + cell_B(t-1) ========
            float g[8];
            if (t < T_STEPS - 1) {
                #pragma unroll
                for (int e = 0; e < 8; ++e)
                    g[e] = feats[((size_t)((t + 1) * C_IN + 8 * wv + e) << 16) + gbase];
            }
            float4_t faccA = fcb;
            gemm(accA, cur, nxt, 0, faccA, t > 0);
            if (t > 0) store_fc(t - 1, 0, faccA);
            if (t > 0) cell(accB, cB, nxt, 1);   // writes hB[nxt] tiles {2,3}

            __syncthreads();   // B1

            // ======== P2: GEMM_B(t)+FC_B(t-1) + cell_A(t) ========
            float4_t faccB = fcb;
            gemm(accB, cur, nxt, 1, faccB, t > 0);
            if (t > 0) store_fc(t - 1, 1, faccB);
            cell(accA, cA, cur, 0);              // writes hB[cur] tiles {0,1}

            if (t < T_STEPS - 1) {
                uint4_t pk = { cvt_pk(g[0], g[1]), cvt_pk(g[2], g[3]),
                               cvt_pk(g[4], g[5]), cvt_pk(g[6], g[7]) };
                *(uint4_t*)&xB[nxt][xtile][xoff] = pk;
            }

            __syncthreads();   // B2
        }

        // epilogue: cell_B(31) -> hB[1]; FC of both chains for t=31
        cell(accB, cB, 1, 1);
        __syncthreads();
        do_fc(T_STEPS - 1, 1, 0);
        do_fc(T_STEPS - 1, 1, 1);
        __syncthreads();   // pass isolation before re-zero
    }
}

extern "C" void kernel_launch(void* const* d_in, const int* in_sizes, int n_in,
                              void* d_out, int out_size, void* d_ws, size_t ws_size,
                              hipStream_t stream) {
    const float* feats = (const float*)d_in[0];
    const float* W_ih  = (const float*)d_in[1];
    const float* W_hh  = (const float*)d_in[2];
    const float* b_ih  = (const float*)d_in[3];
    const float* b_hh  = (const float*)d_in[4];
    const float* fc_w  = (const float*)d_in[5];
    const float* fc_b  = (const float*)d_in[6];
    float* out = (float*)d_out;

    lstmconv_mfma<<<NBLK, NTHR, 0, stream>>>(feats, W_ih, W_hh, b_ih, b_hh,
                                             fc_w, fc_b, out);
}

// Round 13
// 156.788 us; speedup vs baseline: 2.8090x; 2.8090x over previous
//
#include <hip/hip_runtime.h>
#include <stdint.h>

// LSTMConv via MFMA — R11 structure (157us) with RAW BARRIERS in the hot
// loop: __syncthreads() forces s_waitcnt vmcnt(0) before s_barrier (m97:
// documented compiler behavior), draining (a) gather loads issued in P1
// but consumed in P2-end and (b) the 8 scattered FC stores, every phase.
// LDS visibility only needs lgkmcnt(0) -> use asm waitcnt + s_barrier;
// VMEM ops stay in flight across barriers, compiler inserts vmcnt at the
// actual use sites. Cold-path barriers stay __syncthreads().
//
// Chain A = p 0..31 (n-tiles 0,1), chain B = p 32..63 (n-tiles 2,3).
//   P1: gather-issue(t+1), GEMM_A(t)+FC_A(t-1) merged, cell_B(t-1)
//   P2: GEMM_B(t)+FC_B(t-1) merged, cell_A(t), x-pack(t+1)
// Weights + bias persistent in VGPRs; x/h LDS pre-packed as MFMA B-frags
// (conflict-free ds_read_b128), double-buffered. exp2-folded activations,
// raw v_exp_f32 (R11 fix).

#define T_STEPS 32
#define C_IN    64
#define HID     128
#define OUT_F   64
#define BP      64
#define NBLK    256            // 16384 / BP
#define NTHR    512            // 8 waves

typedef __attribute__((ext_vector_type(8))) short short8_t;
typedef __attribute__((ext_vector_type(4))) short short4_t;
typedef __attribute__((ext_vector_type(4))) float float4_t;
typedef __attribute__((ext_vector_type(4))) unsigned int uint4_t;

#define L2E 1.44269504088896340736f

__device__ __forceinline__ short f2bf(float f) {
    uint32_t u = __builtin_bit_cast(uint32_t, f);
    u += 0x7fff + ((u >> 16) & 1);   // RNE
    return (short)(u >> 16);
}
__device__ __forceinline__ uint32_t cvt_pk(float lo, float hi) {
    uint32_t r;
    asm("v_cvt_pk_bf16_f32 %0, %1, %2" : "=v"(r) : "v"(lo), "v"(hi));
    return r;
}
// raw-trans activations: one v_exp_f32 + one v_rcp_f32 each
__device__ __forceinline__ float sig2(float a) {   // a pre-scaled by L2E
    return __builtin_amdgcn_rcpf(1.0f + __builtin_amdgcn_exp2f(-a));
}
__device__ __forceinline__ float th2(float a) {    // a pre-scaled by 2*L2E
    return fmaf(-2.0f,
                __builtin_amdgcn_rcpf(1.0f + __builtin_amdgcn_exp2f(a)),
                1.0f);
}
// barrier that waits ONLY on LDS ops (lgkmcnt), leaving VMEM in flight
__device__ __forceinline__ void barrier_lgkm() {
    asm volatile("s_waitcnt lgkmcnt(0)" ::: "memory");
    __builtin_amdgcn_s_barrier();
    asm volatile("" ::: "memory");
}

__global__ __launch_bounds__(NTHR, 2) void lstmconv_mfma(
    const float* __restrict__ feats,
    const float* __restrict__ W_ih,
    const float* __restrict__ W_hh,
    const float* __restrict__ b_ih,
    const float* __restrict__ b_hh,
    const float* __restrict__ fc_w,
    const float* __restrict__ fc_b,
    float* __restrict__ out)
{
    __shared__ __align__(16) short xB[2][8][512];    // 16 KB
    __shared__ __align__(16) short hB[2][16][512];   // 32 KB

    const int tid  = threadIdx.x;
    const int lane = tid & 63;
    const int wv   = tid >> 6;       // wave 0..7; owns gate rows 16wv..16wv+16
    const int i16  = lane & 15;
    const int g4   = lane >> 4;
    const int p0   = blockIdx.x * BP;

    // ---------- one-time init ----------
    for (int i = tid; i < 2 * 16 * 512 / 2; i += NTHR)
        ((uint32_t*)hB)[i] = 0u;                     // h_{-1}=0 in BOTH bufs

    // Gate-W A-fragments, persistent, log2e-scaled:
    // row = 128*gi + 16*wv + i16 ; k = 32*kt + 8*g4 + e  (kt<2 -> W_ih)
    short8_t wfrag[4][6];
    float4_t bias_r[4];
    #pragma unroll
    for (int gi = 0; gi < 4; ++gi) {
        int row = 128 * gi + 16 * wv + i16;
        float sc = (gi == 2) ? 2.0f * L2E : L2E;
        #pragma unroll
        for (int kt = 0; kt < 6; ++kt) {
            int kk = 32 * kt + 8 * g4;
            const float* src = (kt < 2) ? &W_ih[row * C_IN + kk]
                                        : &W_hh[row * HID + (kk - 64)];
            short8_t f;
            #pragma unroll
            for (int e = 0; e < 8; ++e) f[e] = f2bf(src[e] * sc);
            wfrag[gi][kt] = f;
        }
        int g0 = 128 * gi + 16 * wv + 4 * g4;
        float4_t bi = *(const float4_t*)&b_ih[g0];
        float4_t bh = *(const float4_t*)&b_hh[g0];
        #pragma unroll
        for (int r = 0; r < 4; ++r) bias_r[gi][r] = (bi[r] + bh[r]) * sc;
    }

    // FC: wave -> m-tile m2=wv&3 (out rows 16m2..+16), local n-tile nl=wv>>2.
    const int m2  = wv & 3;
    const int nl  = wv >> 2;         // 0 or 1 within the chain
    short8_t fcfrag[4];
    #pragma unroll
    for (int kt = 0; kt < 4; ++kt) {
        int kk = 32 * kt + 8 * g4;
        const float* src = &fc_w[(16 * m2 + i16) * HID + kk];
        short8_t f;
        #pragma unroll
        for (int e = 0; e < 8; ++e) f[e] = f2bf(src[e]);
        fcfrag[kt] = f;
    }
    const float4_t fcb = *(const float4_t*)&fc_b[16 * m2 + 4 * g4];

    // gather: thread loads channels c = 8*wv + e, pixel p = lane
    const int prow  = 2 * (p0 >> 7) + 1;
    const int pcol0 = 2 * (p0 & 127) + 1;
    const int gbase = prow * 256 + pcol0 + 2 * lane;
    const int xtile = (wv >> 2) * 4 + (lane >> 4);           // kt*4 + nt
    const int xoff  = ((lane & 15) + 16 * (wv & 3)) * 8;
    const int htile_base = (wv >> 1) * 4;                    // + global nt
    const int hoff  = (i16 + 16 * (2 * (wv & 1) + (g4 >> 1))) * 8 + 4 * (g4 & 1);

    // prologue: gather x_0 -> xB[0]
    {
        float g[8];
        #pragma unroll
        for (int e = 0; e < 8; ++e)
            g[e] = feats[((size_t)(8 * wv + e) << 16) + gbase];
        uint4_t pk = { cvt_pk(g[0], g[1]), cvt_pk(g[2], g[3]),
                       cvt_pk(g[4], g[5]), cvt_pk(g[6], g[7]) };
        *(uint4_t*)&xB[0][xtile][xoff] = pk;
    }

    float4_t accA[4][2], accB[4][2], cA[2], cB[2];
    #pragma unroll
    for (int nt = 0; nt < 2; ++nt) {
        cA[nt] = (float4_t){0.f, 0.f, 0.f, 0.f};
        cB[nt] = (float4_t){0.f, 0.f, 0.f, 0.f};
    }

    // store FC result for step tf of `chain`
    auto store_fc = [&](int tf, int chain, const float4_t& facc) {
        int ntg = chain * 2 + nl;
        #pragma unroll
        for (int r = 0; r < 4; ++r)
            out[((size_t)(tf * OUT_F + 16 * m2 + 4 * g4 + r) << 14)
                + p0 + 16 * ntg + i16] = facc[r];
    };

    // standalone FC (epilogue): h in hB[hb]
    auto do_fc = [&](int tf, int hb, int chain) {
        int ntg = chain * 2 + nl;
        float4_t facc = fcb;
        #pragma unroll
        for (int kt = 0; kt < 4; ++kt) {
            short8_t b = *(const short8_t*)&hB[hb][kt * 4 + ntg][lane * 8];
            facc = __builtin_amdgcn_mfma_f32_16x16x32_bf16(
                fcfrag[kt], b, facc, 0, 0, 0);
        }
        store_fc(tf, chain, facc);
    };

    // gates = bias + W @ [x(xb); h(hb)] for `chain`; FC(t-1) merged on the
    // shared h fragments (kt 2..5) when nt == nl.
    auto gemm = [&](float4_t (&acc)[4][2], int xb, int hb, int chain,
                    float4_t& facc, bool fc_on) {
        #pragma unroll
        for (int gi = 0; gi < 4; ++gi)
            #pragma unroll
            for (int nt = 0; nt < 2; ++nt) acc[gi][nt] = bias_r[gi];
        #pragma unroll
        for (int nt = 0; nt < 2; ++nt) {
            int ntg = chain * 2 + nt;
            short8_t bf[6];
            #pragma unroll
            for (int kt = 0; kt < 6; ++kt) {
                const short* src = (kt < 2) ? &xB[xb][kt * 4 + ntg][0]
                                            : &hB[hb][(kt - 2) * 4 + ntg][0];
                bf[kt] = *(const short8_t*)&src[lane * 8];
            }
            #pragma unroll
            for (int kt = 0; kt < 6; ++kt)
                #pragma unroll
                for (int gi = 0; gi < 4; ++gi)
                    acc[gi][nt] = __builtin_amdgcn_mfma_f32_16x16x32_bf16(
                        wfrag[gi][kt], bf[kt], acc[gi][nt], 0, 0, 0);
            if (fc_on && nt == nl) {
                #pragma unroll
                for (int kt = 2; kt < 6; ++kt)
                    facc = __builtin_amdgcn_mfma_f32_16x16x32_bf16(
                        fcfrag[kt - 2], bf[kt], facc, 0, 0, 0);
            }
        }
    };

    // cell update (i,f,g,o) for `chain`; writes h into hB[hb]
    auto cell = [&](float4_t (&acc)[4][2], float4_t (&c)[2], int hb, int chain) {
        #pragma unroll
        for (int nt = 0; nt < 2; ++nt) {
            float4_t cv = c[nt];
            float hv[4];
            #pragma unroll
            for (int r = 0; r < 4; ++r) {
                float ig = sig2(acc[0][nt][r]);
                float fg = sig2(acc[1][nt][r]);
                float cand = th2(acc[2][nt][r]);
                float og = sig2(acc[3][nt][r]);
                float cn = fmaf(fg, cv[r], ig * cand);
                cv[r] = cn;
                hv[r] = og * th2(cn * (2.0f * L2E));
            }
            c[nt] = cv;
            uint32_t h0 = cvt_pk(hv[0], hv[1]);
            uint32_t h1 = cvt_pk(hv[2], hv[3]);
            uint32_t* dst = (uint32_t*)&hB[hb][htile_base + chain * 2 + nt][hoff];
            dst[0] = h0; dst[1] = h1;
        }
    };

    __syncthreads();   // cold: xB[0] ready, hB zeroed

    #pragma unroll 1
    for (int t = 0; t < T_STEPS; ++t) {
        const int cur = t & 1;
        const int nxt = cur ^ 1;   // holds h(t-1) of both chains

        // ======== P1: GEMM_A(t)+FC_A(t-1) + cell_B(t-1) ========
        float g[8];
        if (t < T_STEPS - 1) {
            #pragma unroll
            for (int e = 0; e < 8; ++e)
                g[e] = feats[((size_t)((t + 1) * C_IN + 8 * wv + e) << 16) + gbase];
        }
        float4_t faccA = fcb;
        gemm(accA, cur, nxt, 0, faccA, t > 0);
        if (t > 0) store_fc(t - 1, 0, faccA);
        if (t > 0) cell(accB, cB, nxt, 1);   // writes hB[nxt] tiles {2,3}

        barrier_lgkm();   // B1: LDS-only wait; gather loads/FC stores fly on

        // ======== P2: GEMM_B(t)+FC_B(t-1) + cell_A(t) ========
        float4_t faccB = fcb;
        gemm(accB, cur, nxt, 1, faccB, t > 0);
        if (t > 0) store_fc(t - 1, 1, faccB);
        cell(accA, cA, cur, 0);              // writes hB[cur] tiles {0,1}

        if (t < T_STEPS - 1) {
            uint4_t pk = { cvt_pk(g[0], g[1]), cvt_pk(g[2], g[3]),
                           cvt_pk(g[4], g[5]), cvt_pk(g[6], g[7]) };
            *(uint4_t*)&xB[nxt][xtile][xoff] = pk;
        }

        barrier_lgkm();   // B2
    }

    // epilogue: cell_B(31) -> hB[1]; FC of both chains for t=31 (h in hB[1])
    cell(accB, cB, 1, 1);
    __syncthreads();   // cold
    do_fc(T_STEPS - 1, 1, 0);
    do_fc(T_STEPS - 1, 1, 1);
}

extern "C" void kernel_launch(void* const* d_in, const int* in_sizes, int n_in,
                              void* d_out, int out_size, void* d_ws, size_t ws_size,
                              hipStream_t stream) {
    const float* feats = (const float*)d_in[0];
    const float* W_ih  = (const float*)d_in[1];
    const float* W_hh  = (const float*)d_in[2];
    const float* b_ih  = (const float*)d_in[3];
    const float* b_hh  = (const float*)d_in[4];
    const float* fc_w  = (const float*)d_in[5];
    const float* fc_b  = (const float*)d_in[6];
    float* out = (float*)d_out;

    lstmconv_mfma<<<NBLK, NTHR, 0, stream>>>(feats, W_ih, W_hh, b_ih, b_hh,
                                             fc_w, fc_b, out);
}